// Round 12
// baseline (752.440 us; speedup 1.0000x reference)
//
#include <hip/hip_runtime.h>
#include <math.h>

#define N_PATHS 50000
#define N_LINKS 10000
#define LPATH   8
#define DEG     40
#define DIM     64
#define G3      192
#define ITERS   8
#define HP      76   // htile pitch (ushorts): 152B rows -> ~4-way worst-case conflicts

typedef float f32x4  __attribute__((ext_vector_type(4)));
typedef short bf16x8 __attribute__((ext_vector_type(8)));

__device__ __forceinline__ float fsigmoid(float x){ return 1.0f/(1.0f + __expf(-x)); }
__device__ __forceinline__ float ftanh(float x){ return 1.0f - 2.0f/(__expf(2.0f*x) + 1.0f); }
__device__ __forceinline__ unsigned short bf16_rne(float v){
  unsigned u = __float_as_uint(v);
  return (unsigned short)((u + 0x7FFFu + ((u>>16)&1u)) >> 16);
}
__device__ __forceinline__ unsigned pack_bf16(float a, float b){
  unsigned r;
  asm("v_cvt_pk_bf16_f32 %0, %1, %2" : "=v"(r) : "v"(a), "v"(b));
  return r;
}
__device__ __forceinline__ float lo16f(unsigned v){ return __uint_as_float(v << 16); }
__device__ __forceinline__ float hi16f(unsigned v){ return __uint_as_float(v & 0xFFFF0000u); }
__device__ __forceinline__ void split8(const float* s, bf16x8& hi, bf16x8& lo){
  #pragma unroll
  for (int e=0;e<8;e++){
    unsigned short hb = bf16_rne(s[e]);
    float lof = s[e] - __uint_as_float(((unsigned)hb)<<16);
    hi[e] = (short)hb; lo[e] = (short)bf16_rne(lof);
  }
}
__device__ __forceinline__ void accum8(float* a, uint4 v){
  unsigned x[4] = {v.x, v.y, v.z, v.w};
  #pragma unroll
  for (int q=0;q<4;q++){
    a[2*q]   += __uint_as_float((x[q]&0xFFFFu)<<16);
    a[2*q+1] += __uint_as_float(x[q]&0xFFFF0000u);
  }
}

// ---------------- path embedding ----------------
__global__ __launch_bounds__(256) void path_embed(
    const float* __restrict__ ft, const float* __restrict__ fp, const float* __restrict__ fps,
    const float* __restrict__ w1, const float* __restrict__ b1,
    const float* __restrict__ w2, const float* __restrict__ b2,
    float* __restrict__ path_state)
{
  __shared__ float h1[4][DIM];
  int j  = threadIdx.x & 63;
  int pl = threadIdx.x >> 6;
  int p  = blockIdx.x*4 + pl;
  float x0 = ft[p]*1e-4f, x1 = fp[p]*1e-3f, x2 = fps[p]*1e-3f;
  float h = b1[j] + x0*w1[0*DIM+j] + x1*w1[1*DIM+j] + x2*w1[2*DIM+j];
  h1[pl][j] = fmaxf(h, 0.f);
  __syncthreads();
  float acc = b2[j];
  #pragma unroll 8
  for (int k=0;k<DIM;k++) acc = fmaf(h1[pl][k], w2[k*DIM+j], acc);
  path_state[p*DIM+j] = fmaxf(acc, 0.f);
}

// ---------------- link embedding ----------------
__global__ __launch_bounds__(256) void link_embed(
    const float* __restrict__ ft, const float* __restrict__ cap, const int* __restrict__ ptl,
    const float* __restrict__ w1, const float* __restrict__ b1,
    const float* __restrict__ w2, const float* __restrict__ b2,
    float* __restrict__ link_state)
{
  __shared__ float h1[4][DIM];
  int j  = threadIdx.x & 63;
  int wl = threadIdx.x >> 6;
  int l  = blockIdx.x*4 + wl;
  float s = 0.f;
  if (j < DEG) s = ft[ptl[(l*DEG + j)*2 + 0]];
  #pragma unroll
  for (int off=32; off; off>>=1) s += __shfl_down(s, off);
  float load = __shfl(s, 0) / (cap[l]*1e9f);
  float x0 = cap[l]*1e-5f;
  float h = b1[j] + x0*w1[0*DIM+j] + load*w1[1*DIM+j];
  h1[wl][j] = fmaxf(h, 0.f);
  __syncthreads();
  float acc = b2[j];
  #pragma unroll 8
  for (int k=0;k<DIM;k++) acc = fmaf(h1[wl][k], w2[k*DIM+j], acc);
  link_state[l*DIM+j] = fmaxf(acc, 0.f);
}

// ---------------- pack 4 weight mats into bf16 MFMA fragments ----------------
__global__ __launch_bounds__(256) void pack_frags(
    const float* __restrict__ pg_wh, const float* __restrict__ pg_wx,
    const float* __restrict__ lg_wx, const float* __restrict__ lg_wh,
    unsigned short* __restrict__ whf)
{
  int tid = blockIdx.x*256 + threadIdx.x;
  if (tid >= 4*24*512) return;
  int i = tid & 7, l = (tid>>3)&63, f = (tid>>9)%24, m = tid/(24*512);
  int nt = f>>1, kc = f&1;
  int k = kc*32 + (l>>4)*8 + i;
  int n = nt*16 + (l&15);
  const float* src = (m==0)?pg_wh : (m==1)?pg_wx : (m==2)?lg_wx : lg_wh;
  whf[tid] = bf16_rne(src[k*G3 + n]);
}

// ---------------- initial LX, packed bf16, 384 B/link (per-XCD L2-resident) ----------------
__global__ __launch_bounds__(192) void compute_lx(
    const float* __restrict__ link_state, const float* __restrict__ wx,
    const float* __restrict__ bx, const float* __restrict__ bh,
    unsigned short* __restrict__ LXq)
{
  __shared__ float ls[4][DIM];
  int g  = threadIdx.x;
  int l0 = blockIdx.x*4;
  if (g < DIM){
    #pragma unroll
    for (int li=0; li<4; li++) ls[li][g] = link_state[(l0+li)*DIM+g];
  }
  __syncthreads();
  float b = bx[g] + (g < 128 ? bh[g] : 0.f);
  float a0=b, a1=b, a2=b, a3=b;
  #pragma unroll 8
  for (int k=0;k<DIM;k++){
    float w = wx[k*G3+g];
    a0 = fmaf(ls[0][k], w, a0);
    a1 = fmaf(ls[1][k], w, a1);
    a2 = fmaf(ls[2][k], w, a2);
    a3 = fmaf(ls[3][k], w, a3);
  }
  int comp = g >> 6, dim = g & 63;
  int pos = dim*3 + comp;
  LXq[(size_t)(l0+0)*G3+pos]=bf16_rne(a0);
  LXq[(size_t)(l0+1)*G3+pos]=bf16_rne(a1);
  LXq[(size_t)(l0+2)*G3+pos]=bf16_rne(a2);
  LXq[(size_t)(l0+3)*G3+pos]=bf16_rne(a3);
}

// ---------------- MFMA 8-step GRU scan: wave-private, ZERO barriers in t-loop ----------------
// Each wave owns 16 paths x ALL 64 dims: 24 MFMAs + all gates per step.
// h round-trip through wave-private LDS (same-wave DS ops are FIFO -> no sync needed).
// Weights in block LDS (one barrier at start). Lane l: path lr=l&15, dim-group lg=l>>4.
__global__ __launch_bounds__(256) void path_scan_mfma(
    const unsigned short* __restrict__ LXq, const int* __restrict__ ltp,
    const unsigned short* __restrict__ whf, const float* __restrict__ bh,
    float* __restrict__ path_state, unsigned short* __restrict__ seq16)
{
  __shared__ __align__(16) unsigned short bw_lds[24*512];   // 24.5 KB weight fragments
  __shared__ __align__(16) unsigned short htile[4][16*HP];  // per-wave h (bf16)
  __shared__ float bq_lds[DIM];                             // bh q-part
  __shared__ int ltps[4][128];
  int tid = threadIdx.x, l = tid & 63, w = tid >> 6;
  int lg = l >> 4, lr = l & 15;
  int p0 = blockIdx.x*64 + w*16;
  if (p0 > N_PATHS-16) p0 = N_PATHS-16;   // duplicate waves write identical data

  { const uint4* src=(const uint4*)whf; uint4* dst=(uint4*)bw_lds;
    #pragma unroll
    for (int i=0;i<6;i++) dst[i*256+tid] = src[i*256+tid]; }
  if (tid < DIM) bq_lds[tid] = bh[128 + tid];

  *(int2*)&ltps[w][l*2] = *(const int2*)(ltp + (size_t)p0*LPATH + l*2);

  // initial h: fp32 hold for this lane's 16 dims (4 runs of 4), bf16 copy into htile
  f32x4 hold[4];
  #pragma unroll
  for (int t4=0;t4<4;t4++){
    hold[t4] = *(const f32x4*)(path_state + (size_t)(p0+lr)*DIM + t4*16 + lg*4);
    uint2 u = make_uint2(pack_bf16(hold[t4][0], hold[t4][1]), pack_bf16(hold[t4][2], hold[t4][3]));
    *(uint2*)&htile[w][lr*HP + t4*16 + lg*4] = u;
  }

  __syncthreads();   // weights + bq visible; htile/ltps are wave-private

  unsigned short* seqp = seq16 + ((size_t)(p0+lr)*LPATH)*DIM;

  for (int t=0; t<LPATH; t++){
    // 1) LX gather for all 16 dims of path lr (12 x uint2, consumed ~500cy later)
    int lk = ltps[w][lr*LPATH + t];
    const unsigned short* lx = LXq + (size_t)lk*G3;
    uint2 xa[4][3];
    #pragma unroll
    for (int t4=0;t4<4;t4++){
      #pragma unroll
      for (int jj=0;jj<3;jj++)
        xa[t4][jj] = *(const uint2*)(lx + t4*48 + lg*12 + jj*4);
    }
    // 2) B-frags (previous h) + 24 MFMAs, 12 independent acc chains
    bf16x8 h0 = *(const bf16x8*)&htile[w][lr*HP +  0 + lg*8];
    bf16x8 h1 = *(const bf16x8*)&htile[w][lr*HP + 32 + lg*8];
    f32x4 acc[12];
    #pragma unroll
    for (int nt=0;nt<8;nt++) acc[nt] = (f32x4){0.f,0.f,0.f,0.f};
    #pragma unroll
    for (int t4=0;t4<4;t4++) acc[8+t4] = *(const f32x4*)&bq_lds[t4*16 + lg*4];
    #pragma unroll
    for (int nt=0;nt<12;nt++){
      bf16x8 w0 = *(const bf16x8*)&bw_lds[(nt*2+0)*512 + l*8];
      acc[nt] = __builtin_amdgcn_mfma_f32_16x16x32_bf16(w0, h0, acc[nt], 0,0,0);
      bf16x8 w1 = *(const bf16x8*)&bw_lds[(nt*2+1)*512 + l*8];
      acc[nt] = __builtin_amdgcn_mfma_f32_16x16x32_bf16(w1, h1, acc[nt], 0,0,0);
    }
    // 3) gates for all 16 dims; write h_new to wave-private htile + seq16
    #pragma unroll
    for (int t4=0;t4<4;t4++){
      // 12 ushorts per t4: (z0,r0)(q0,z1)(r1,q1)(z2,r2)(q2,z3)(r3,q3)
      float lz[4]  = { lo16f(xa[t4][0].x), hi16f(xa[t4][0].y), lo16f(xa[t4][1].y), hi16f(xa[t4][2].x) };
      float lrr[4] = { hi16f(xa[t4][0].x), lo16f(xa[t4][1].x), hi16f(xa[t4][1].y), lo16f(xa[t4][2].y) };
      float lq[4]  = { lo16f(xa[t4][0].y), hi16f(xa[t4][1].x), lo16f(xa[t4][2].x), hi16f(xa[t4][2].y) };
      f32x4 hn;
      #pragma unroll
      for (int r=0;r<4;r++){
        float z  = fsigmoid(lz[r]  + acc[t4][r]);
        float rr = fsigmoid(lrr[r] + acc[4+t4][r]);
        float hh = ftanh(lq[r] + rr*acc[8+t4][r]);
        hn[r] = z*hold[t4][r] + (1.f-z)*hh;
      }
      hold[t4] = hn;
      uint2 u = make_uint2(pack_bf16(hn[0], hn[1]), pack_bf16(hn[2], hn[3]));
      *(uint2*)&htile[w][lr*HP + t4*16 + lg*4] = u;
      *(uint2*)(seqp + (size_t)t*DIM + t4*16 + lg*4) = u;
    }
    // no barrier: next step's B-frag reads are same-wave DS ops, FIFO-ordered after writes
  }
  #pragma unroll
  for (int t4=0;t4<4;t4++)
    *(f32x4*)(path_state + (size_t)(p0+lr)*DIM + t4*16 + lg*4) = hold[t4];
}

// ---------------- fused link update: 4-wave parallel GRU + next LX ----------------
__global__ __launch_bounds__(256) void link_fused(
    const unsigned short* __restrict__ seq16, const int* __restrict__ ptl,
    const unsigned short* __restrict__ whf,
    const float* __restrict__ lbx, const float* __restrict__ lbh,
    const float* __restrict__ pbx, const float* __restrict__ pbh,
    float* __restrict__ link_state, unsigned short* __restrict__ LXq)
{
  __shared__ float pspart[4][16][64];
  __shared__ float tile[16*68];
  int tid = threadIdx.x, l = tid & 63, w = tid >> 6;
  int lr = l & 15, lg = l >> 4;
  int l0 = blockIdx.x*16;

  float ps[16];
  #pragma unroll
  for (int i=0;i<16;i++) ps[i]=0.f;
  {
    const int* pe = ptl + (size_t)(l0+lr)*DEG*2 + w*10*2;
    #pragma unroll
    for (int d=0; d<10; d++){
      int pp = pe[2*d], tt = pe[2*d+1];
      const unsigned short* rowp = seq16 + ((size_t)pp*LPATH + (tt-1))*DIM;
      accum8(ps,   *(const uint4*)(rowp + lg*8));
      accum8(ps+8, *(const uint4*)(rowp + 32 + lg*8));
    }
  }
  #pragma unroll
  for (int i=0;i<16;i++) pspart[w][i][l] = ps[i];
  __syncthreads();

  #pragma unroll
  for (int i=0;i<16;i++)
    ps[i] = pspart[0][i][l] + pspart[1][i][l] + pspart[2][i][l] + pspart[3][i][l];

  bf16x8 phi[2], plo[2], lhi[2], llo[2];
  #pragma unroll
  for (int kc=0;kc<2;kc++){
    split8(ps + kc*8, phi[kc], plo[kc]);
    float hs[8];
    const float* lsr = link_state + (size_t)(l0+lr)*DIM + kc*32 + lg*8;
    *(f32x4*)hs = *(const f32x4*)lsr;
    *(f32x4*)(hs+4) = *(const f32x4*)(lsr+4);
    split8(hs, lhi[kc], llo[kc]);
  }
  f32x4 mxa[3], mha[3];
  #pragma unroll
  for (int j=0;j<3;j++){
    int nt = w + j*4;
    float bxv = lbx[nt*16+lr], bhv = lbh[nt*16+lr];
    mxa[j] = (f32x4){bxv,bxv,bxv,bxv};
    mha[j] = (f32x4){bhv,bhv,bhv,bhv};
    #pragma unroll
    for (int kc=0;kc<2;kc++){
      bf16x8 bwx = *(const bf16x8*)(whf + (size_t)((2*24 + nt*2+kc)*512) + l*8);
      mxa[j] = __builtin_amdgcn_mfma_f32_16x16x32_bf16(phi[kc], bwx, mxa[j], 0,0,0);
      mxa[j] = __builtin_amdgcn_mfma_f32_16x16x32_bf16(plo[kc], bwx, mxa[j], 0,0,0);
      bf16x8 bwh = *(const bf16x8*)(whf + (size_t)((3*24 + nt*2+kc)*512) + l*8);
      mha[j] = __builtin_amdgcn_mfma_f32_16x16x32_bf16(lhi[kc], bwh, mha[j], 0,0,0);
      mha[j] = __builtin_amdgcn_mfma_f32_16x16x32_bf16(llo[kc], bwh, mha[j], 0,0,0);
    }
  }
  __syncthreads();

  #pragma unroll
  for (int r=0;r<4;r++){
    size_t lk = (size_t)(l0 + lg*4 + r)*DIM + w*16 + lr;
    float lsv = link_state[lk];
    float z  = fsigmoid(mxa[0][r] + mha[0][r]);
    float rr = fsigmoid(mxa[1][r] + mha[1][r]);
    float hh = ftanh(mxa[2][r] + rr*mha[2][r]);
    float hn = z*lsv + (1.f-z)*hh;
    link_state[lk] = hn;
    tile[(lg*4+r)*68 + w*16 + lr] = hn;
  }
  __syncthreads();

  f32x4 lxa[3];
  #pragma unroll
  for (int j=0;j<3;j++){
    int g = (w + j*4)*16 + lr;
    float b = pbx[g] + (g < 128 ? pbh[g] : 0.f);
    lxa[j] = (f32x4){b,b,b,b};
  }
  #pragma unroll
  for (int kc=0;kc<2;kc++){
    float hs[8];
    #pragma unroll
    for (int i=0;i<8;i++) hs[i] = tile[lr*68 + kc*32 + lg*8 + i];
    bf16x8 thi, tlo; split8(hs, thi, tlo);
    #pragma unroll
    for (int j=0;j<3;j++){
      int nt = w + j*4;
      bf16x8 bw = *(const bf16x8*)(whf + (size_t)((1*24 + nt*2+kc)*512) + l*8);
      lxa[j] = __builtin_amdgcn_mfma_f32_16x16x32_bf16(thi, bw, lxa[j], 0,0,0);
      lxa[j] = __builtin_amdgcn_mfma_f32_16x16x32_bf16(tlo, bw, lxa[j], 0,0,0);
    }
  }
  #pragma unroll
  for (int r=0;r<4;r++){
    int link = l0 + lg*4 + r;
    size_t base = (size_t)link*G3 + (size_t)(w*16 + lr)*3;
    LXq[base+0] = bf16_rne(lxa[0][r]);
    LXq[base+1] = bf16_rne(lxa[1][r]);
    LXq[base+2] = bf16_rne(lxa[2][r]);
  }
}

// ---------------- readout: LDS-staged coalesced reads (r10 version) ----------------
__global__ __launch_bounds__(256) void readout(
    const unsigned short* __restrict__ seq16, const int* __restrict__ ltp,
    const float* __restrict__ cap,
    const float* __restrict__ w1, const float* __restrict__ b1,
    const float* __restrict__ w2, const float* __restrict__ b2,
    const float* __restrict__ w3, const float* __restrict__ b3,
    float* __restrict__ out)
{
  __shared__ unsigned short rows_sh[4][64*72];
  __shared__ float w1s[DIM*32];
  __shared__ float w2s[32*16];
  __shared__ float w3s[16];
  __shared__ float b1s[32], b2s[16];
  int tid = threadIdx.x;
  for (int i=tid;i<DIM*32;i+=256) w1s[i]=w1[i];
  for (int i=tid;i<32*16;i+=256) w2s[i]=w2[i];
  if (tid<16) w3s[tid]=w3[tid];
  if (tid<32) b1s[tid]=b1[tid];
  if (tid<16) b2s[tid]=b2[tid];
  __syncthreads();

  int l = tid & 63, w = tid >> 6;
  size_t wave_r = (size_t)blockIdx.x*256 + (size_t)w*64;
  if (wave_r >= (size_t)N_PATHS*LPATH) return;

  const unsigned short* src = seq16 + wave_r*DIM;
  #pragma unroll
  for (int i=0;i<16;i++){
    int e  = i*64 + l;
    int ri = e >> 4;
    int c4 = e & 15;
    *(uint2*)&rows_sh[w][ri*72 + c4*4] = *(const uint2*)(src + (size_t)e*4);
  }

  size_t row = wave_r + l;
  const unsigned short* myrow = &rows_sh[w][l*72];
  float a[32];
  #pragma unroll
  for (int j=0;j<32;j++) a[j]=b1s[j];
  #pragma unroll
  for (int c=0;c<16;c++){
    uint2 v = *(const uint2*)(myrow + c*4);
    float f0 = __uint_as_float((v.x & 0xFFFFu) << 16);
    float f1 = __uint_as_float(v.x & 0xFFFF0000u);
    float f2 = __uint_as_float((v.y & 0xFFFFu) << 16);
    float f3 = __uint_as_float(v.y & 0xFFFF0000u);
    #pragma unroll
    for (int j=0;j<32;j++) a[j] = fmaf(f0, w1s[(c*4+0)*32+j], a[j]);
    #pragma unroll
    for (int j=0;j<32;j++) a[j] = fmaf(f1, w1s[(c*4+1)*32+j], a[j]);
    #pragma unroll
    for (int j=0;j<32;j++) a[j] = fmaf(f2, w1s[(c*4+2)*32+j], a[j]);
    #pragma unroll
    for (int j=0;j<32;j++) a[j] = fmaf(f3, w1s[(c*4+3)*32+j], a[j]);
  }
  float h2[16];
  #pragma unroll
  for (int j2=0;j2<16;j2++) h2[j2]=b2s[j2];
  #pragma unroll
  for (int j=0;j<32;j++){
    float hv = fmaxf(a[j],0.f);
    #pragma unroll
    for (int j2=0;j2<16;j2++) h2[j2] = fmaf(hv, w2s[j*16+j2], h2[j2]);
  }
  float o = b3[0];
  #pragma unroll
  for (int j2=0;j2<16;j2++) o = fmaf(fmaxf(h2[j2],0.f), w3s[j2], o);
  float sp = (o > 20.f) ? o : log1pf(__expf(o));
  float dly = sp / cap[ltp[row]];
  dly += __shfl_xor(dly, 1);
  dly += __shfl_xor(dly, 2);
  dly += __shfl_xor(dly, 4);
  if ((l & 7) == 0) out[row >> 3] = dly;
}

extern "C" void kernel_launch(void* const* d_in, const int* in_sizes, int n_in,
                              void* d_out, int out_size, void* d_ws, size_t ws_size,
                              hipStream_t stream) {
  const float* ft    = (const float*)d_in[0];
  const float* fpk   = (const float*)d_in[1];
  const float* fps   = (const float*)d_in[2];
  const float* cap   = (const float*)d_in[3];
  const int*   ltp   = (const int*)  d_in[4];
  const int*   ptl   = (const int*)  d_in[5];
  const float* pe_w1 = (const float*)d_in[6];
  const float* pe_b1 = (const float*)d_in[7];
  const float* pe_w2 = (const float*)d_in[8];
  const float* pe_b2 = (const float*)d_in[9];
  const float* le_w1 = (const float*)d_in[10];
  const float* le_b1 = (const float*)d_in[11];
  const float* le_w2 = (const float*)d_in[12];
  const float* le_b2 = (const float*)d_in[13];
  const float* pg_wx = (const float*)d_in[14];
  const float* pg_wh = (const float*)d_in[15];
  const float* pg_bx = (const float*)d_in[16];
  const float* pg_bh = (const float*)d_in[17];
  const float* lg_wx = (const float*)d_in[18];
  const float* lg_wh = (const float*)d_in[19];
  const float* lg_bx = (const float*)d_in[20];
  const float* lg_bh = (const float*)d_in[21];
  const float* ro_w1 = (const float*)d_in[22];
  const float* ro_b1 = (const float*)d_in[23];
  const float* ro_w2 = (const float*)d_in[24];
  const float* ro_b2 = (const float*)d_in[25];
  const float* ro_w3 = (const float*)d_in[26];
  const float* ro_b3 = (const float*)d_in[27];
  float* out = (float*)d_out;

  float* path_state = (float*)d_ws;
  float* link_state = path_state + (size_t)N_PATHS*DIM;
  unsigned short* LXq   = (unsigned short*)(link_state + (size_t)N_LINKS*DIM);  // 10000*192
  unsigned short* seq16 = LXq + (size_t)N_LINKS*G3;
  unsigned short* whf   = seq16 + (size_t)N_PATHS*LPATH*DIM;

  path_embed<<<N_PATHS/4, 256, 0, stream>>>(ft, fpk, fps, pe_w1, pe_b1, pe_w2, pe_b2, path_state);
  link_embed<<<N_LINKS/4, 256, 0, stream>>>(ft, cap, ptl, le_w1, le_b1, le_w2, le_b2, link_state);
  pack_frags<<<192, 256, 0, stream>>>(pg_wh, pg_wx, lg_wx, lg_wh, whf);
  compute_lx<<<N_LINKS/4, 192, 0, stream>>>(link_state, pg_wx, pg_bx, pg_bh, LXq);
  for (int it=0; it<ITERS; ++it){
    path_scan_mfma<<<(N_PATHS+63)/64, 256, 0, stream>>>(LXq, ltp, whf, pg_bh, path_state, seq16);
    if (it < ITERS-1)
      link_fused<<<N_LINKS/16, 256, 0, stream>>>(seq16, ptl, whf,
          lg_bx, lg_bh, pg_bx, pg_bh, link_state, LXq);
  }
  readout<<<(N_PATHS*LPATH + 255)/256, 256, 0, stream>>>(seq16, ltp, cap,
      ro_w1, ro_b1, ro_w2, ro_b2, ro_w3, ro_b3, out);
}